// Round 13
// baseline (158.423 us; speedup 1.0000x reference)
//
#include <hip/hip_runtime.h>
#include <cstdint>
#include <cstddef>

#define NN 16   // neighbors
#define DI 32
#define DO 64

typedef short bf16x8 __attribute__((ext_vector_type(8)));
typedef short bf16x4 __attribute__((ext_vector_type(4)));
typedef float f32x4 __attribute__((ext_vector_type(4)));

#if defined(__has_builtin)
#  if __has_builtin(__builtin_amdgcn_mfma_f32_16x16x16_bf16)
#    define MFMA_K16(a, b, c) __builtin_amdgcn_mfma_f32_16x16x16_bf16(a, b, c, 0, 0, 0)
#    define HAVE_K16 1
#  elif __has_builtin(__builtin_amdgcn_mfma_f32_16x16x16bf16_1k)
#    define MFMA_K16(a, b, c) __builtin_amdgcn_mfma_f32_16x16x16bf16_1k(a, b, c, 0, 0, 0)
#    define HAVE_K16 1
#  endif
#endif

// ---------- tables ----------
__device__ __constant__ int c_INV[12][6] = {
  {0,1,2,3,4,5},{0,5,4,3,2,1},{4,3,0,5,2,1},{1,2,4,3,5,0},
  {3,5,2,0,4,1},{1,4,3,5,0,2},{4,0,3,1,2,5},{1,0,2,4,3,5},
  {4,1,2,5,0,3},{3,1,4,0,2,5},{2,1,4,5,3,0},{4,5,0,3,1,2}};
__device__ __constant__ int c_ROLL[5][6] = {
  {0,1,2,3,4,5},{0,2,3,4,5,1},{0,3,4,5,1,2},{0,4,5,1,2,3},{0,5,1,2,3,4}};
__device__ __constant__ float c_VS[12][3] = {
  {0.f, 0.5257311121f, 0.8506508084f},
  {0.f, 0.5257311121f, -0.8506508084f},
  {0.f, -0.5257311121f, 0.8506508084f},
  {0.f, -0.5257311121f, -0.8506508084f},
  {0.5257311121f, 0.8506508084f, 0.f},
  {0.5257311121f, -0.8506508084f, 0.f},
  {-0.5257311121f, 0.8506508084f, 0.f},
  {-0.5257311121f, -0.8506508084f, 0.f},
  {0.8506508084f, 0.f, 0.5257311121f},
  {0.8506508084f, 0.f, -0.5257311121f},
  {-0.8506508084f, 0.f, 0.5257311121f},
  {-0.8506508084f, 0.f, -0.5257311121f}};
__device__ __constant__ int c_C2V[6][2] = {{0,1},{6,7},{2,11},{4,9},{5,8},{3,10}};

// ---------- helpers ----------
// Exact RNE f32->bf16, compiler-visible ops only.
__device__ inline unsigned int bfround(float f) {
  unsigned int u = __float_as_uint(f);
  return u + 0x7fffu + ((u >> 16) & 1u);
}
__device__ inline unsigned int pk2(float a, float b) {
  return __builtin_amdgcn_perm(bfround(b), bfround(a), 0x07060302u);
}
__device__ inline unsigned short f2bf_fast(float a) {
  return (unsigned short)(bfround(a) >> 16);
}
__device__ inline uint4 pack8(const float* v8) {
  uint4 o4;
  o4.x = pk2(v8[0], v8[1]);
  o4.y = pk2(v8[2], v8[3]);
  o4.z = pk2(v8[4], v8[5]);
  o4.w = pk2(v8[6], v8[7]);
  return o4;
}

// int8 nfm storage, scale S=64, bytes stored BIASED (+128).
// Encode: magic-add fmaf(clamp(x),64, 1.5*2^23+128) -> low mantissa byte is
// (q+128)&0xFF with RNE. Decode: perm byte-insert into 0x4B000000, subtract
// 2^23+128 (exact), bf16 pack = rounding-free perm (|q|<=127 exact in bf16).
__device__ inline unsigned int q4i8(f32x4 o) {
  const float M = 12583040.0f;   // 1.5*2^23 + 128 (bias folded in)
  unsigned int u0 = __float_as_uint(fmaf(fminf(fmaxf(o[0], -1.984375f), 1.984375f), 64.f, M));
  unsigned int u1 = __float_as_uint(fmaf(fminf(fmaxf(o[1], -1.984375f), 1.984375f), 64.f, M));
  unsigned int u2 = __float_as_uint(fmaf(fminf(fmaxf(o[2], -1.984375f), 1.984375f), 64.f, M));
  unsigned int u3 = __float_as_uint(fmaf(fminf(fmaxf(o[3], -1.984375f), 1.984375f), 64.f, M));
  unsigned int p01 = __builtin_amdgcn_perm(u1, u0, 0x00000400u);  // b1=u1.b0 b0=u0.b0
  unsigned int p23 = __builtin_amdgcn_perm(u3, u2, 0x00000400u);
  return __builtin_amdgcn_perm(p23, p01, 0x05040100u);            // (q3,q2,q1,q0) biased
}
__device__ inline bf16x8 dec8(uint2 w) {
  const float B = 8388736.0f;    // 2^23 + 128
  const unsigned int C = 0x4B000000u;
  float f0 = __uint_as_float(__builtin_amdgcn_perm(C, w.x, 0x07060500u)) - B;
  float f1 = __uint_as_float(__builtin_amdgcn_perm(C, w.x, 0x07060501u)) - B;
  float f2 = __uint_as_float(__builtin_amdgcn_perm(C, w.x, 0x07060502u)) - B;
  float f3 = __uint_as_float(__builtin_amdgcn_perm(C, w.x, 0x07060503u)) - B;
  float f4 = __uint_as_float(__builtin_amdgcn_perm(C, w.y, 0x07060500u)) - B;
  float f5 = __uint_as_float(__builtin_amdgcn_perm(C, w.y, 0x07060501u)) - B;
  float f6 = __uint_as_float(__builtin_amdgcn_perm(C, w.y, 0x07060502u)) - B;
  float f7 = __uint_as_float(__builtin_amdgcn_perm(C, w.y, 0x07060503u)) - B;
  union { unsigned int u[4]; bf16x8 v8; } o;
  o.u[0] = __builtin_amdgcn_perm(__float_as_uint(f1), __float_as_uint(f0), 0x07060302u);
  o.u[1] = __builtin_amdgcn_perm(__float_as_uint(f3), __float_as_uint(f2), 0x07060302u);
  o.u[2] = __builtin_amdgcn_perm(__float_as_uint(f5), __float_as_uint(f4), 0x07060302u);
  o.u[3] = __builtin_amdgcn_perm(__float_as_uint(f7), __float_as_uint(f6), 0x07060302u);
  return o.v8;
}

// ---------- k0a: the ONLY k12 prerequisites (A_bf + wdB), tiny ----------
__global__ __launch_bounds__(256) void k0a_expand(
    const float* __restrict__ Wdir, const float* __restrict__ Wdim,
    unsigned short* __restrict__ A_bf, unsigned short* __restrict__ wdB) {
  int idx = blockIdx.x * 256 + threadIdx.x;
  if (idx < 27648) {
    int chunk = idx;
    int rl = chunk & 15, u = chunk >> 4;
    int q = u & 3; u >>= 2;
    int ks = u % 6, rt = u / 6;
    int row = rt * 16 + rl;
    int h = row / 144;
    int k = (row / 12) % 12, r = row % 12;
    int ci0 = ks * 32 + q * 8;
    const float* wsrc = Wdir + h * 576;
    int c = ci0 / 6, i = ci0 - c * 6;
    float v8[8];
    #pragma unroll
    for (int j = 0; j < 8; ++j) {
      int jj = c_INV[r][i];
      int off;
      if (k == 0)       off = (jj == 0) ? 0 : 1;
      else if (k == 1)  off = (jj == 0) ? 2 : 3;
      else { int a = (k - 2) / 5, rr = (k - 2) % 5; off = 6 + a * 6 + c_ROLL[rr][jj]; }
      v8[j] = 0.5f * wsrc[c * 18 + off];
      ++i; if (i == 6) { i = 0; ++c; }
    }
    *(uint4*)(A_bf + (size_t)chunk * 8) = pack8(v8);
  } else if (idx < 27776) {
    int e = idx - 27648;   // 0..127
    int lane = e & 63, ot = e >> 6;
    float v8[8];
    #pragma unroll
    for (int j = 0; j < 8; ++j) {
      int kk = ((lane >> 4) & 3) * 8 + j;
      int o = ot * 16 + (lane & 15);
      v8[j] = Wdim[kk * 32 + o];
    }
    *(uint4*)(wdB + (size_t)e * 8) = pack8(v8);
  }
}

// ---------- k12f: k12 blocks + k0b backfill, launched as TWO half-dispatches ----------
// INSTRUMENTATION ROUND: with one 60us k12f, the top-5-by-duration table can
// never show k3_feat (bench repeats ~20 iters -> top-5 = 5x the slowest
// kernel). Splitting k12f into two ~30us halves (each with both k12 and k0b
// blocks -> full occupancy per dispatch) forces k3 into the top-5 with full
// counters next round. Math/layout bit-identical to R11/R12.
__global__ __launch_bounds__(256, 4) void k12f_main(
    const int* __restrict__ nbi, const float* __restrict__ verts,
    const float* __restrict__ fm, const float* __restrict__ Wdim,
    const unsigned short* __restrict__ wdB,
    const unsigned short* __restrict__ A_bf,
    unsigned char* __restrict__ nfm,
    const float* __restrict__ W,
    unsigned short* __restrict__ W2k,
    unsigned short* __restrict__ Wck,
    unsigned short* __restrict__ fmTbf,
    float* __restrict__ out_fm, int V,
    int bid0, int h12, int h0b) {
  __shared__ __align__(16) unsigned short in_bf[2][96][40];  // 15360 B
  __shared__ __align__(16) float de_s[2][96];                // 768 B
  __shared__ __align__(16) unsigned short crossL[2][192][20];// 15360 B
  int nblk12 = V / 2;
  int local = blockIdx.x;
  int bid = (local < h12) ? (bid0 * h12 + local)
                          : (nblk12 + bid0 * h0b + (local - h12));

  if (bid >= nblk12) {
    // ================= k0b: weight expansion bulk =================
    int idx = (bid - nblk12) * 256 + threadIdx.x;
    int nF = 24 * V;
    if (idx < 239616) {
      const float* wsrc; unsigned short* dst;
      int k, r, ci0; float scale;
      if (idx < 221184) {
        int chunk = idx;
        int d = chunk & 63, u = chunk >> 6;
        int q = u & 3; u >>= 2;
        int ks = u % 6, kr = u / 6;
        k = kr / 12; r = kr % 12;
        ci0 = ks * 32 + q * 8;
        wsrc = W + d * 576;
        dst = W2k + (size_t)chunk * 8;
        scale = 0.015625f;            // 1/64: dequant for int8 nfm
      } else {
        int chunk = idx - 221184;
        int d = chunk & 63, u = chunk >> 6;
        int q = u & 3; u >>= 2;
        int ks = u % 6;
        r = u / 6; k = 12;
        ci0 = ks * 32 + q * 8;
        wsrc = W + d * 576;
        dst = Wck + (size_t)chunk * 8;
        scale = 1.0f;
      }
      int c = ci0 / 6, i = ci0 - c * 6;
      float v8[8];
      #pragma unroll
      for (int j = 0; j < 8; ++j) {
        int jj = c_INV[r][i];
        int off;
        if (k == 0)       off = (jj == 0) ? 0 : 1;
        else if (k == 1)  off = (jj == 0) ? 2 : 3;
        else if (k == 12) off = (jj == 0) ? 4 : 5;
        else { int a = (k - 2) / 5, rr = (k - 2) % 5; off = 6 + a * 6 + c_ROLL[rr][jj]; }
        v8[j] = scale * wsrc[c * 18 + off];
        ++i; if (i == 6) { i = 0; ++c; }
      }
      *(uint4*)dst = pack8(v8);
    } else if (idx < 239616 + nF) {
      int chunk = idx - 239616;
      int p = chunk / 24, cc = chunk - p * 24;
      int ci0 = cc * 8;
      int c = ci0 / 6, i = ci0 - c * 6;
      float v8[8];
      #pragma unroll
      for (int j = 0; j < 8; ++j) {
        v8[j] = fm[((size_t)c * V + p) * 6 + i];
        ++i; if (i == 6) { i = 0; ++c; }
      }
      *(uint4*)(fmTbf + (size_t)chunk * 8) = pack8(v8);
    } else if (idx < 239616 + nF + 48 * V) {
      int x4 = idx - (239616 + nF);
      ((float4*)out_fm)[x4] = ((const float4*)fm)[x4];
    }
    return;
  }

  // ================= k12: proven R9 structure (2 vertices, 4 waves) =================
  int t = threadIdx.x;
  int w = t >> 6, lane = t & 63;
  int quad = lane >> 4, col = lane & 15;
  int p0 = bid * 2;
  int v = w & 1, hf = w >> 1;
  int p = p0 + v;

  // ---- phase G: gather ----
  for (int i = lane; i < 256; i += 64) {
    int n = i >> 4, c = hf * 16 + (i & 15);
    int nb = nbi[p * 16 + n];
    const float* src = fm + ((size_t)c * V + nb) * 6;
    float2 a  = *(const float2*)(src + 0);
    float2 b  = *(const float2*)(src + 2);
    float2 cd = *(const float2*)(src + 4);
    unsigned short* dst = &in_bf[v][n * 6][c];
    dst[0 * 40] = f2bf_fast(a.x);
    dst[1 * 40] = f2bf_fast(a.y);
    dst[2 * 40] = f2bf_fast(b.x);
    dst[3 * 40] = f2bf_fast(b.y);
    dst[4 * 40] = f2bf_fast(cd.x);
    dst[5 * 40] = f2bf_fast(cd.y);
  }
  if (hf == 0 && lane < 16) {
    int n = lane, nb = nbi[p * 16 + n];
    float px = verts[p * 3 + 0], py = verts[p * 3 + 1], pz = verts[p * 3 + 2];
    float qx = verts[nb * 3 + 0] - px, qy = verts[nb * 3 + 1] - py, qz = verts[nb * 3 + 2] - pz;
    float L = sqrtf(qx * qx + qy * qy + qz * qz);
    float inv = 1.0f / fmaxf(L, 1e-12f);
    qx *= inv; qy *= inv; qz *= inv;
    float de[12];
    #pragma unroll
    for (int vv = 0; vv < 12; ++vv)
      de[vv] = c_VS[vv][0] * qx + c_VS[vv][1] * qy + c_VS[vv][2] * qz;
    #pragma unroll
    for (int j = 0; j < 6; ++j)
      de_s[v][n * 6 + j] = fmaxf(de[c_C2V[j][0]], de[c_C2V[j][1]]);
  }
  __syncthreads();

  // ---- phase C: cross MFMA, all 4 waves (wave -> vertex w&1, 3 mt each) ----
  {
    int vv = w & 1;
    int mtb = (w >> 1) * 3;
    bf16x8 Bf[2];
    #pragma unroll
    for (int ot = 0; ot < 2; ++ot)
      Bf[ot] = *(const bf16x8*)(wdB + (size_t)(ot * 64 + lane) * 8);
    float wd32[2] = {Wdim[1024 + col], Wdim[1024 + 16 + col]};
    #pragma unroll
    for (int mi = 0; mi < 3; ++mi) {
      int mt = mtb + mi;
      bf16x8 a0 = *(const bf16x8*)&in_bf[vv][mt * 16 + col][quad * 8];
      f32x4 du = *(const f32x4*)&de_s[vv][mt * 16 + quad * 4];
      #pragma unroll
      for (int ot = 0; ot < 2; ++ot) {
        f32x4 acc = (f32x4){0.f, 0.f, 0.f, 0.f};
        acc = __builtin_amdgcn_mfma_f32_16x16x32_bf16(a0, Bf[ot], acc, 0, 0, 0);
        #pragma unroll
        for (int r = 0; r < 4; ++r)
          acc[r] = fmaf(du[r], wd32[ot], acc[r]);
        #pragma unroll
        for (int r = 0; r < 4; ++r) {
          int m = mt * 16 + quad * 4 + r;
          int n = m / 6, i = m - n * 6;
          crossL[vv][(ot * 16 + col) * 6 + i][n] = f2bf_fast(acc[r]);
        }
      }
    }
  }
  __syncthreads();

  // ---- build Afr from crossL (transpose reads, one-time) ----
  bf16x8 Afr[2][6];
  #pragma unroll
  for (int pi = 0; pi < 2; ++pi) {
    #pragma unroll
    for (int ks = 0; ks < 6; ++ks) {
      union { unsigned short s[8]; bf16x8 v8; } u;
      #pragma unroll
      for (int j = 0; j < 8; ++j)
        u.s[j] = crossL[pi][ks * 32 + quad * 8 + j][col];
      Afr[pi][ks] = u.v8;
    }
  }

  // ---- phase T: 18 tile iterations per wave, barrier-free, prefetched ----
  bf16x8 wf[6];
  {
    const unsigned short* Abase = A_bf + w * 3072 + quad * 128 + col * 8;
    #pragma unroll
    for (int ks = 0; ks < 6; ++ks) wf[ks] = *(const bf16x8*)(Abase + ks * 512);
  }
  for (int rt = w; rt < 72; rt += 4) {
    int h = rt / 9;
    f32x4 acc[2];
    acc[0] = (f32x4){0.f, 0.f, 0.f, 0.f};
    acc[1] = (f32x4){0.f, 0.f, 0.f, 0.f};
    #pragma unroll
    for (int ks = 0; ks < 6; ++ks) {
      acc[0] = __builtin_amdgcn_mfma_f32_16x16x32_bf16(Afr[0][ks], wf[ks], acc[0], 0, 0, 0);
      acc[1] = __builtin_amdgcn_mfma_f32_16x16x32_bf16(Afr[1][ks], wf[ks], acc[1], 0, 0, 0);
    }
    // prefetch next tile's A fragments (clamped; unused garbage on last iter)
    bf16x8 wfn[6];
    {
      int rtn = min(rt + 4, 71);
      const unsigned short* AbaseN = A_bf + rtn * 3072 + quad * 128 + col * 8;
      #pragma unroll
      for (int ks = 0; ks < 6; ++ks) wfn[ks] = *(const bf16x8*)(AbaseN + ks * 512);
    }
    int row0 = h * 24 + col;
    int row1 = min(h * 24 + 16 + col, 191);
    #pragma unroll
    for (int pi = 0; pi < 2; ++pi) {
      // ---- softmax over n (no max-subtraction; logits bounded) ----
      float e0 = __expf(acc[pi][0]), e1 = __expf(acc[pi][1]);
      float e2 = __expf(acc[pi][2]), e3 = __expf(acc[pi][3]);
      float s = (e0 + e1) + (e2 + e3);
      s += __shfl_xor(s, 16);
      s += __shfl_xor(s, 32);
      float inv = __builtin_amdgcn_rcpf(s);
      unsigned int lo = pk2(e0 * inv, e1 * inv);
      unsigned int hi = pk2(e2 * inv, e3 * inv);
      f32x4 o0 = (f32x4){0.f, 0.f, 0.f, 0.f}, o1 = o0;
#ifdef HAVE_K16
      union { uint2 u; bf16x4 v4; } bcvt;
      bcvt.u = make_uint2(lo, hi);
      bf16x4 a0 = *(const bf16x4*)&crossL[pi][row0][quad * 4];
      bf16x4 a1 = *(const bf16x4*)&crossL[pi][row1][quad * 4];
      o0 = MFMA_K16(a0, bcvt.v4, o0);
      o1 = MFMA_K16(a1, bcvt.v4, o1);
#else
      int s0l = quad * 32 + col, s1l = s0l + 16;
      unsigned int b0 = (unsigned int)__shfl((int)lo, s0l);
      unsigned int b1 = (unsigned int)__shfl((int)hi, s0l);
      unsigned int b2 = (unsigned int)__shfl((int)lo, s1l);
      unsigned int b3 = (unsigned int)__shfl((int)hi, s1l);
      bool vq = (quad < 2);
      union { uint4 u; bf16x8 v8; } cvt;
      cvt.u = make_uint4(vq ? b0 : 0u, vq ? b1 : 0u, vq ? b2 : 0u, vq ? b3 : 0u);
      union { unsigned short sv[8]; bf16x8 v8; } ua0, ua1;
      #pragma unroll
      for (int j = 0; j < 8; ++j) {
        int nn = quad * 8 + j;
        ua0.sv[j] = (nn < 16) ? crossL[pi][row0][nn] : (unsigned short)0;
        ua1.sv[j] = (nn < 16) ? crossL[pi][row1][nn] : (unsigned short)0;
      }
      o0 = __builtin_amdgcn_mfma_f32_16x16x32_bf16(ua0.v8, cvt.v8, o0, 0, 0, 0);
      o1 = __builtin_amdgcn_mfma_f32_16x16x32_bf16(ua1.v8, cvt.v8, o1, 0, 0, 0);
#endif
      size_t rowbase = (size_t)bid * 55296 + (size_t)(rt * 16 + col) * 48 + pi * 24;
      *(unsigned int*)(nfm + rowbase + quad * 4) = q4i8(o0);
      if (quad < 2)
        *(unsigned int*)(nfm + rowbase + 16 + quad * 4) = q4i8(o1);
    }
    #pragma unroll
    for (int ks = 0; ks < 6; ++ks) wf[ks] = wfn[ks];
  }
}

// ---------- k3: MFMA feat GEMMs + center + fused c2v max -> out ----------
// nfm int8 (biased bytes) [pg][1152][48]; dec8 = perm-insert + sub + exact
// bf16 perm-pack.
__global__ __launch_bounds__(512) void k3_feat(
    const unsigned short* __restrict__ W2k,
    const unsigned short* __restrict__ Wck,
    const unsigned short* __restrict__ fmTbf,
    const unsigned char* __restrict__ nfm,
    float* __restrict__ out, int V) {
  __shared__ float red[2][3][16][64];   // 24576 B
  int pb = blockIdx.x, j = blockIdx.y;
  int t = threadIdx.x, w = t >> 6, lane = t & 63;
  int rhalf = w >> 2, kw = w & 3;
  int r = c_C2V[j][rhalf];
  int quad = lane >> 4, col = lane & 15;
  int p0 = pb * 16;
  f32x4 acc[4];
  #pragma unroll
  for (int m = 0; m < 4; ++m) acc[m] = (f32x4){0.f, 0.f, 0.f, 0.f};

  int base24[6];
  #pragma unroll
  for (int ks = 0; ks < 6; ++ks) {
    int ci = ks * 32 + quad * 8;
    int hh = ci / 24, oo = ci - hh * 24;
    base24[ks] = hh * 6912 + oo;   // hh*144*48 + oo (bytes)
  }

  int pA = p0 + col;
  const unsigned char* Bn0 = nfm + (size_t)(pA >> 1) * 55296 + (pA & 1) * 24;
  const unsigned short* Bc0 = fmTbf + (size_t)pA * 192;

  int nkb = (kw == 3) ? 4 : 3;
  for (int i = 0; i < nkb; ++i) {
    int kb = kw * 3 + i;   // kw=3,i=3 -> 12 (center)
    const unsigned short* Ab;
    int kr48 = 0;
    if (kb < 12) { Ab = W2k + (size_t)(kb * 12 + r) * 12288; kr48 = (kb * 12 + r) * 48; }
    else         { Ab = Wck + (size_t)r * 12288; }
    const unsigned short* Albase = Ab + quad * 512 + col * 8;
    #pragma unroll
    for (int ks = 0; ks < 6; ++ks) {
      bf16x8 b0;
      if (kb < 12) {
        b0 = dec8(*(const uint2*)(Bn0 + base24[ks] + kr48));
      } else {
        b0 = *(const bf16x8*)(Bc0 + ks * 32 + quad * 8);
      }
      #pragma unroll
      for (int m = 0; m < 4; ++m) {
        bf16x8 a = *(const bf16x8*)(Albase + ks * 2048 + m * 128);
        acc[m] = __builtin_amdgcn_mfma_f32_16x16x32_bf16(a, b0, acc[m], 0, 0, 0);
      }
    }
  }
  if (kw > 0) {
    #pragma unroll
    for (int m = 0; m < 4; ++m)
      #pragma unroll
      for (int rr = 0; rr < 4; ++rr)
        red[rhalf][kw - 1][m * 4 + rr][lane] = acc[m][rr];
  }
  __syncthreads();
  if (kw == 0) {
    #pragma unroll
    for (int m = 0; m < 4; ++m)
      #pragma unroll
      for (int rr = 0; rr < 4; ++rr) {
        int ri = m * 4 + rr;
        acc[m][rr] += red[rhalf][0][ri][lane] + red[rhalf][1][ri][lane] + red[rhalf][2][ri][lane];
      }
  }
  if (w == 4) {
    #pragma unroll
    for (int m = 0; m < 4; ++m)
      #pragma unroll
      for (int rr = 0; rr < 4; ++rr)
        red[1][0][m * 4 + rr][lane] = acc[m][rr];
  }
  __syncthreads();
  if (w == 0) {
    #pragma unroll
    for (int m = 0; m < 4; ++m)
      #pragma unroll
      for (int rr = 0; rr < 4; ++rr) {
        float vmax = fmaxf(acc[m][rr], red[1][0][m * 4 + rr][lane]);
        int d = m * 16 + quad * 4 + rr;
        out[((size_t)d * V + p0 + col) * 6 + j] = vmax;
      }
  }
}

// ---------- host ----------
extern "C" void kernel_launch(void* const* d_in, const int* in_sizes, int n_in,
                              void* d_out, int out_size, void* d_ws, size_t ws_size,
                              hipStream_t stream) {
  const int* nbi = (const int*)d_in[0];
  const float* verts = (const float*)d_in[1];
  const float* fm = (const float*)d_in[2];
  const float* Wdim = (const float*)d_in[3];
  const float* W = (const float*)d_in[4];
  const float* Wdir = (const float*)d_in[5];
  float* out = (float*)d_out;
  float* ws = (float*)d_ws;
  int V = in_sizes[0] / NN;   // 2048

  unsigned short* A_bf  = (unsigned short*)ws;             // 221184 ush
  unsigned short* W2k   = (unsigned short*)(ws + 110592);  // 1769472 ush
  unsigned short* Wck   = (unsigned short*)(ws + 995328);  // 147456 ush
  unsigned short* fmTbf = (unsigned short*)(ws + 1069056); // 192*V ush
  size_t o = 1069056 + (size_t)96 * V;
  unsigned char* nfm = (unsigned char*)(ws + o);           // 27648*V BYTES [pg][1152][48] int8 biased
  o += (size_t)6912 * V;
  unsigned short* wdB = (unsigned short*)(ws + o);         // 1024 ush

  // k0a: A_bf + wdB only (k12 prerequisites), 27776 threads
  k0a_expand<<<109, 256, 0, stream>>>(Wdir, Wdim, A_bf, wdB);
  // k12f split into two half-dispatches (instrumentation: lets k3_feat reach
  // the top-5 counter table). Each half: h12 k12-blocks + h0b k0b-blocks.
  int nblk12 = V / 2;                            // 1024
  int n0b = 239616 + 24 * V + 48 * V;            // k0b thread count
  int nb0b = (n0b + 255) / 256;                  // 1512 at V=2048
  int h12 = nblk12 / 2;                          // 512
  int h0b = nb0b / 2;                            // 756
  k12f_main<<<h12 + h0b, 256, 0, stream>>>(nbi, verts, fm, Wdim, wdB, A_bf, nfm,
                                           W, W2k, Wck, fmTbf,
                                           out + (size_t)DO * V * 6, V, 0, h12, h0b);
  k12f_main<<<(nblk12 - h12) + (nb0b - h0b), 256, 0, stream>>>(
                                           nbi, verts, fm, Wdim, wdB, A_bf, nfm,
                                           W, W2k, Wck, fmTbf,
                                           out + (size_t)DO * V * 6, V, 1, h12, h0b);
  k3_feat<<<dim3(V / 16, 6), 512, 0, stream>>>(W2k, Wck, fmTbf, nfm, out, V);
}

// Round 14
// 149.261 us; speedup vs baseline: 1.0614x; 1.0614x over previous
//
#include <hip/hip_runtime.h>
#include <cstdint>
#include <cstddef>

#define NN 16   // neighbors
#define DI 32
#define DO 64

typedef short bf16x8 __attribute__((ext_vector_type(8)));
typedef short bf16x4 __attribute__((ext_vector_type(4)));
typedef float f32x4 __attribute__((ext_vector_type(4)));

#if defined(__has_builtin)
#  if __has_builtin(__builtin_amdgcn_mfma_f32_16x16x16_bf16)
#    define MFMA_K16(a, b, c) __builtin_amdgcn_mfma_f32_16x16x16_bf16(a, b, c, 0, 0, 0)
#    define HAVE_K16 1
#  elif __has_builtin(__builtin_amdgcn_mfma_f32_16x16x16bf16_1k)
#    define MFMA_K16(a, b, c) __builtin_amdgcn_mfma_f32_16x16x16bf16_1k(a, b, c, 0, 0, 0)
#    define HAVE_K16 1
#  endif
#endif

// ---------- tables ----------
__device__ __constant__ int c_INV[12][6] = {
  {0,1,2,3,4,5},{0,5,4,3,2,1},{4,3,0,5,2,1},{1,2,4,3,5,0},
  {3,5,2,0,4,1},{1,4,3,5,0,2},{4,0,3,1,2,5},{1,0,2,4,3,5},
  {4,1,2,5,0,3},{3,1,4,0,2,5},{2,1,4,5,3,0},{4,5,0,3,1,2}};
__device__ __constant__ int c_ROLL[5][6] = {
  {0,1,2,3,4,5},{0,2,3,4,5,1},{0,3,4,5,1,2},{0,4,5,1,2,3},{0,5,1,2,3,4}};
__device__ __constant__ float c_VS[12][3] = {
  {0.f, 0.5257311121f, 0.8506508084f},
  {0.f, 0.5257311121f, -0.8506508084f},
  {0.f, -0.5257311121f, 0.8506508084f},
  {0.f, -0.5257311121f, -0.8506508084f},
  {0.5257311121f, 0.8506508084f, 0.f},
  {0.5257311121f, -0.8506508084f, 0.f},
  {-0.5257311121f, 0.8506508084f, 0.f},
  {-0.5257311121f, -0.8506508084f, 0.f},
  {0.8506508084f, 0.f, 0.5257311121f},
  {0.8506508084f, 0.f, -0.5257311121f},
  {-0.8506508084f, 0.f, 0.5257311121f},
  {-0.8506508084f, 0.f, -0.5257311121f}};
__device__ __constant__ int c_C2V[6][2] = {{0,1},{6,7},{2,11},{4,9},{5,8},{3,10}};

// ---------- helpers ----------
// Exact RNE f32->bf16, compiler-visible ops only.
__device__ inline unsigned int bfround(float f) {
  unsigned int u = __float_as_uint(f);
  return u + 0x7fffu + ((u >> 16) & 1u);
}
__device__ inline unsigned int pk2(float a, float b) {
  return __builtin_amdgcn_perm(bfround(b), bfround(a), 0x07060302u);
}
__device__ inline unsigned short f2bf_fast(float a) {
  return (unsigned short)(bfround(a) >> 16);
}
__device__ inline uint4 pack8(const float* v8) {
  uint4 o4;
  o4.x = pk2(v8[0], v8[1]);
  o4.y = pk2(v8[2], v8[3]);
  o4.z = pk2(v8[4], v8[5]);
  o4.w = pk2(v8[6], v8[7]);
  return o4;
}

// int8 nfm storage, scale S=64, bytes stored BIASED (+128).
// Encode: magic-add fmaf(clamp(x),64, 1.5*2^23+128) -> low mantissa byte is
// (q+128)&0xFF with RNE. Decode: perm byte-insert into 0x4B000000, subtract
// 2^23+128 (exact), bf16 pack = rounding-free perm (|q|<=127 exact in bf16).
__device__ inline unsigned int q4i8(f32x4 o) {
  const float M = 12583040.0f;   // 1.5*2^23 + 128 (bias folded in)
  unsigned int u0 = __float_as_uint(fmaf(fminf(fmaxf(o[0], -1.984375f), 1.984375f), 64.f, M));
  unsigned int u1 = __float_as_uint(fmaf(fminf(fmaxf(o[1], -1.984375f), 1.984375f), 64.f, M));
  unsigned int u2 = __float_as_uint(fmaf(fminf(fmaxf(o[2], -1.984375f), 1.984375f), 64.f, M));
  unsigned int u3 = __float_as_uint(fmaf(fminf(fmaxf(o[3], -1.984375f), 1.984375f), 64.f, M));
  unsigned int p01 = __builtin_amdgcn_perm(u1, u0, 0x00000400u);  // b1=u1.b0 b0=u0.b0
  unsigned int p23 = __builtin_amdgcn_perm(u3, u2, 0x00000400u);
  return __builtin_amdgcn_perm(p23, p01, 0x05040100u);            // (q3,q2,q1,q0) biased
}
__device__ inline bf16x8 dec8(uint2 w) {
  const float B = 8388736.0f;    // 2^23 + 128
  const unsigned int C = 0x4B000000u;
  float f0 = __uint_as_float(__builtin_amdgcn_perm(C, w.x, 0x07060500u)) - B;
  float f1 = __uint_as_float(__builtin_amdgcn_perm(C, w.x, 0x07060501u)) - B;
  float f2 = __uint_as_float(__builtin_amdgcn_perm(C, w.x, 0x07060502u)) - B;
  float f3 = __uint_as_float(__builtin_amdgcn_perm(C, w.x, 0x07060503u)) - B;
  float f4 = __uint_as_float(__builtin_amdgcn_perm(C, w.y, 0x07060500u)) - B;
  float f5 = __uint_as_float(__builtin_amdgcn_perm(C, w.y, 0x07060501u)) - B;
  float f6 = __uint_as_float(__builtin_amdgcn_perm(C, w.y, 0x07060502u)) - B;
  float f7 = __uint_as_float(__builtin_amdgcn_perm(C, w.y, 0x07060503u)) - B;
  union { unsigned int u[4]; bf16x8 v8; } o;
  o.u[0] = __builtin_amdgcn_perm(__float_as_uint(f1), __float_as_uint(f0), 0x07060302u);
  o.u[1] = __builtin_amdgcn_perm(__float_as_uint(f3), __float_as_uint(f2), 0x07060302u);
  o.u[2] = __builtin_amdgcn_perm(__float_as_uint(f5), __float_as_uint(f4), 0x07060302u);
  o.u[3] = __builtin_amdgcn_perm(__float_as_uint(f7), __float_as_uint(f6), 0x07060302u);
  return o.v8;
}

// ---------- k0a: the ONLY k12 prerequisites (A_bf + wdB), tiny ----------
__global__ __launch_bounds__(256) void k0a_expand(
    const float* __restrict__ Wdir, const float* __restrict__ Wdim,
    unsigned short* __restrict__ A_bf, unsigned short* __restrict__ wdB) {
  int idx = blockIdx.x * 256 + threadIdx.x;
  if (idx < 27648) {
    int chunk = idx;
    int rl = chunk & 15, u = chunk >> 4;
    int q = u & 3; u >>= 2;
    int ks = u % 6, rt = u / 6;
    int row = rt * 16 + rl;
    int h = row / 144;
    int k = (row / 12) % 12, r = row % 12;
    int ci0 = ks * 32 + q * 8;
    const float* wsrc = Wdir + h * 576;
    int c = ci0 / 6, i = ci0 - c * 6;
    float v8[8];
    #pragma unroll
    for (int j = 0; j < 8; ++j) {
      int jj = c_INV[r][i];
      int off;
      if (k == 0)       off = (jj == 0) ? 0 : 1;
      else if (k == 1)  off = (jj == 0) ? 2 : 3;
      else { int a = (k - 2) / 5, rr = (k - 2) % 5; off = 6 + a * 6 + c_ROLL[rr][jj]; }
      v8[j] = 0.5f * wsrc[c * 18 + off];
      ++i; if (i == 6) { i = 0; ++c; }
    }
    *(uint4*)(A_bf + (size_t)chunk * 8) = pack8(v8);
  } else if (idx < 27776) {
    int e = idx - 27648;   // 0..127
    int lane = e & 63, ot = e >> 6;
    float v8[8];
    #pragma unroll
    for (int j = 0; j < 8; ++j) {
      int kk = ((lane >> 4) & 3) * 8 + j;
      int o = ot * 16 + (lane & 15);
      v8[j] = Wdim[kk * 32 + o];
    }
    *(uint4*)(wdB + (size_t)e * 8) = pack8(v8);
  }
}

// ---------- k12f: k12 blocks [0, V/2) + k0b backfill blocks >= V/2 ----------
// Settled structure (R2-R12): k12 is latency-pinned at ~55us across every
// occupancy/ILP/VALU/write-BW variant; k0b (independent, k3-only outputs)
// backfills the idle issue slots (~8.5us serial -> ~4us marginal). R13's
// two-half split cost 8us and revealed the harness's 256MiB re-poison fill
// (~43us/iter) inside the timed loop + k3 < 43us -> reverted to single
// dispatch (best measured: 150.1).
__global__ __launch_bounds__(256, 4) void k12f_main(
    const int* __restrict__ nbi, const float* __restrict__ verts,
    const float* __restrict__ fm, const float* __restrict__ Wdim,
    const unsigned short* __restrict__ wdB,
    const unsigned short* __restrict__ A_bf,
    unsigned char* __restrict__ nfm,
    const float* __restrict__ W,
    unsigned short* __restrict__ W2k,
    unsigned short* __restrict__ Wck,
    unsigned short* __restrict__ fmTbf,
    float* __restrict__ out_fm, int V) {
  __shared__ __align__(16) unsigned short in_bf[2][96][40];  // 15360 B
  __shared__ __align__(16) float de_s[2][96];                // 768 B
  __shared__ __align__(16) unsigned short crossL[2][192][20];// 15360 B
  int bid = blockIdx.x;
  int nblk12 = V / 2;

  if (bid >= nblk12) {
    // ================= k0b: weight expansion bulk =================
    int idx = (bid - nblk12) * 256 + threadIdx.x;
    int nF = 24 * V;
    if (idx < 239616) {
      const float* wsrc; unsigned short* dst;
      int k, r, ci0; float scale;
      if (idx < 221184) {
        int chunk = idx;
        int d = chunk & 63, u = chunk >> 6;
        int q = u & 3; u >>= 2;
        int ks = u % 6, kr = u / 6;
        k = kr / 12; r = kr % 12;
        ci0 = ks * 32 + q * 8;
        wsrc = W + d * 576;
        dst = W2k + (size_t)chunk * 8;
        scale = 0.015625f;            // 1/64: dequant for int8 nfm
      } else {
        int chunk = idx - 221184;
        int d = chunk & 63, u = chunk >> 6;
        int q = u & 3; u >>= 2;
        int ks = u % 6;
        r = u / 6; k = 12;
        ci0 = ks * 32 + q * 8;
        wsrc = W + d * 576;
        dst = Wck + (size_t)chunk * 8;
        scale = 1.0f;
      }
      int c = ci0 / 6, i = ci0 - c * 6;
      float v8[8];
      #pragma unroll
      for (int j = 0; j < 8; ++j) {
        int jj = c_INV[r][i];
        int off;
        if (k == 0)       off = (jj == 0) ? 0 : 1;
        else if (k == 1)  off = (jj == 0) ? 2 : 3;
        else if (k == 12) off = (jj == 0) ? 4 : 5;
        else { int a = (k - 2) / 5, rr = (k - 2) % 5; off = 6 + a * 6 + c_ROLL[rr][jj]; }
        v8[j] = scale * wsrc[c * 18 + off];
        ++i; if (i == 6) { i = 0; ++c; }
      }
      *(uint4*)dst = pack8(v8);
    } else if (idx < 239616 + nF) {
      int chunk = idx - 239616;
      int p = chunk / 24, cc = chunk - p * 24;
      int ci0 = cc * 8;
      int c = ci0 / 6, i = ci0 - c * 6;
      float v8[8];
      #pragma unroll
      for (int j = 0; j < 8; ++j) {
        v8[j] = fm[((size_t)c * V + p) * 6 + i];
        ++i; if (i == 6) { i = 0; ++c; }
      }
      *(uint4*)(fmTbf + (size_t)chunk * 8) = pack8(v8);
    } else if (idx < 239616 + nF + 48 * V) {
      int x4 = idx - (239616 + nF);
      ((float4*)out_fm)[x4] = ((const float4*)fm)[x4];
    }
    return;
  }

  // ================= k12: proven R9 structure (2 vertices, 4 waves) =================
  int t = threadIdx.x;
  int w = t >> 6, lane = t & 63;
  int quad = lane >> 4, col = lane & 15;
  int p0 = bid * 2;
  int v = w & 1, hf = w >> 1;
  int p = p0 + v;

  // ---- phase G: gather ----
  for (int i = lane; i < 256; i += 64) {
    int n = i >> 4, c = hf * 16 + (i & 15);
    int nb = nbi[p * 16 + n];
    const float* src = fm + ((size_t)c * V + nb) * 6;
    float2 a  = *(const float2*)(src + 0);
    float2 b  = *(const float2*)(src + 2);
    float2 cd = *(const float2*)(src + 4);
    unsigned short* dst = &in_bf[v][n * 6][c];
    dst[0 * 40] = f2bf_fast(a.x);
    dst[1 * 40] = f2bf_fast(a.y);
    dst[2 * 40] = f2bf_fast(b.x);
    dst[3 * 40] = f2bf_fast(b.y);
    dst[4 * 40] = f2bf_fast(cd.x);
    dst[5 * 40] = f2bf_fast(cd.y);
  }
  if (hf == 0 && lane < 16) {
    int n = lane, nb = nbi[p * 16 + n];
    float px = verts[p * 3 + 0], py = verts[p * 3 + 1], pz = verts[p * 3 + 2];
    float qx = verts[nb * 3 + 0] - px, qy = verts[nb * 3 + 1] - py, qz = verts[nb * 3 + 2] - pz;
    float L = sqrtf(qx * qx + qy * qy + qz * qz);
    float inv = 1.0f / fmaxf(L, 1e-12f);
    qx *= inv; qy *= inv; qz *= inv;
    float de[12];
    #pragma unroll
    for (int vv = 0; vv < 12; ++vv)
      de[vv] = c_VS[vv][0] * qx + c_VS[vv][1] * qy + c_VS[vv][2] * qz;
    #pragma unroll
    for (int j = 0; j < 6; ++j)
      de_s[v][n * 6 + j] = fmaxf(de[c_C2V[j][0]], de[c_C2V[j][1]]);
  }
  __syncthreads();

  // ---- phase C: cross MFMA, all 4 waves (wave -> vertex w&1, 3 mt each) ----
  {
    int vv = w & 1;
    int mtb = (w >> 1) * 3;
    bf16x8 Bf[2];
    #pragma unroll
    for (int ot = 0; ot < 2; ++ot)
      Bf[ot] = *(const bf16x8*)(wdB + (size_t)(ot * 64 + lane) * 8);
    float wd32[2] = {Wdim[1024 + col], Wdim[1024 + 16 + col]};
    #pragma unroll
    for (int mi = 0; mi < 3; ++mi) {
      int mt = mtb + mi;
      bf16x8 a0 = *(const bf16x8*)&in_bf[vv][mt * 16 + col][quad * 8];
      f32x4 du = *(const f32x4*)&de_s[vv][mt * 16 + quad * 4];
      #pragma unroll
      for (int ot = 0; ot < 2; ++ot) {
        f32x4 acc = (f32x4){0.f, 0.f, 0.f, 0.f};
        acc = __builtin_amdgcn_mfma_f32_16x16x32_bf16(a0, Bf[ot], acc, 0, 0, 0);
        #pragma unroll
        for (int r = 0; r < 4; ++r)
          acc[r] = fmaf(du[r], wd32[ot], acc[r]);
        #pragma unroll
        for (int r = 0; r < 4; ++r) {
          int m = mt * 16 + quad * 4 + r;
          int n = m / 6, i = m - n * 6;
          crossL[vv][(ot * 16 + col) * 6 + i][n] = f2bf_fast(acc[r]);
        }
      }
    }
  }
  __syncthreads();

  // ---- build Afr from crossL (transpose reads, one-time) ----
  bf16x8 Afr[2][6];
  #pragma unroll
  for (int pi = 0; pi < 2; ++pi) {
    #pragma unroll
    for (int ks = 0; ks < 6; ++ks) {
      union { unsigned short s[8]; bf16x8 v8; } u;
      #pragma unroll
      for (int j = 0; j < 8; ++j)
        u.s[j] = crossL[pi][ks * 32 + quad * 8 + j][col];
      Afr[pi][ks] = u.v8;
    }
  }

  // ---- phase T: 18 tile iterations per wave, barrier-free, prefetched ----
  bf16x8 wf[6];
  {
    const unsigned short* Abase = A_bf + w * 3072 + quad * 128 + col * 8;
    #pragma unroll
    for (int ks = 0; ks < 6; ++ks) wf[ks] = *(const bf16x8*)(Abase + ks * 512);
  }
  for (int rt = w; rt < 72; rt += 4) {
    int h = rt / 9;
    f32x4 acc[2];
    acc[0] = (f32x4){0.f, 0.f, 0.f, 0.f};
    acc[1] = (f32x4){0.f, 0.f, 0.f, 0.f};
    #pragma unroll
    for (int ks = 0; ks < 6; ++ks) {
      acc[0] = __builtin_amdgcn_mfma_f32_16x16x32_bf16(Afr[0][ks], wf[ks], acc[0], 0, 0, 0);
      acc[1] = __builtin_amdgcn_mfma_f32_16x16x32_bf16(Afr[1][ks], wf[ks], acc[1], 0, 0, 0);
    }
    // prefetch next tile's A fragments (clamped; unused garbage on last iter)
    bf16x8 wfn[6];
    {
      int rtn = min(rt + 4, 71);
      const unsigned short* AbaseN = A_bf + rtn * 3072 + quad * 128 + col * 8;
      #pragma unroll
      for (int ks = 0; ks < 6; ++ks) wfn[ks] = *(const bf16x8*)(AbaseN + ks * 512);
    }
    int row0 = h * 24 + col;
    int row1 = min(h * 24 + 16 + col, 191);
    #pragma unroll
    for (int pi = 0; pi < 2; ++pi) {
      // ---- softmax over n (no max-subtraction; logits bounded) ----
      float e0 = __expf(acc[pi][0]), e1 = __expf(acc[pi][1]);
      float e2 = __expf(acc[pi][2]), e3 = __expf(acc[pi][3]);
      float s = (e0 + e1) + (e2 + e3);
      s += __shfl_xor(s, 16);
      s += __shfl_xor(s, 32);
      float inv = __builtin_amdgcn_rcpf(s);
      unsigned int lo = pk2(e0 * inv, e1 * inv);
      unsigned int hi = pk2(e2 * inv, e3 * inv);
      f32x4 o0 = (f32x4){0.f, 0.f, 0.f, 0.f}, o1 = o0;
#ifdef HAVE_K16
      union { uint2 u; bf16x4 v4; } bcvt;
      bcvt.u = make_uint2(lo, hi);
      bf16x4 a0 = *(const bf16x4*)&crossL[pi][row0][quad * 4];
      bf16x4 a1 = *(const bf16x4*)&crossL[pi][row1][quad * 4];
      o0 = MFMA_K16(a0, bcvt.v4, o0);
      o1 = MFMA_K16(a1, bcvt.v4, o1);
#else
      int s0l = quad * 32 + col, s1l = s0l + 16;
      unsigned int b0 = (unsigned int)__shfl((int)lo, s0l);
      unsigned int b1 = (unsigned int)__shfl((int)hi, s0l);
      unsigned int b2 = (unsigned int)__shfl((int)lo, s1l);
      unsigned int b3 = (unsigned int)__shfl((int)hi, s1l);
      bool vq = (quad < 2);
      union { uint4 u; bf16x8 v8; } cvt;
      cvt.u = make_uint4(vq ? b0 : 0u, vq ? b1 : 0u, vq ? b2 : 0u, vq ? b3 : 0u);
      union { unsigned short sv[8]; bf16x8 v8; } ua0, ua1;
      #pragma unroll
      for (int j = 0; j < 8; ++j) {
        int nn = quad * 8 + j;
        ua0.sv[j] = (nn < 16) ? crossL[pi][row0][nn] : (unsigned short)0;
        ua1.sv[j] = (nn < 16) ? crossL[pi][row1][nn] : (unsigned short)0;
      }
      o0 = __builtin_amdgcn_mfma_f32_16x16x32_bf16(ua0.v8, cvt.v8, o0, 0, 0, 0);
      o1 = __builtin_amdgcn_mfma_f32_16x16x32_bf16(ua1.v8, cvt.v8, o1, 0, 0, 0);
#endif
      size_t rowbase = (size_t)bid * 55296 + (size_t)(rt * 16 + col) * 48 + pi * 24;
      *(unsigned int*)(nfm + rowbase + quad * 4) = q4i8(o0);
      if (quad < 2)
        *(unsigned int*)(nfm + rowbase + 16 + quad * 4) = q4i8(o1);
    }
    #pragma unroll
    for (int ks = 0; ks < 6; ++ks) wf[ks] = wfn[ks];
  }
}

// ---------- k3: MFMA feat GEMMs + center + fused c2v max -> out ----------
// nfm int8 (biased bytes) [pg][1152][48]; dec8 = perm-insert + sub + exact
// bf16 perm-pack.
__global__ __launch_bounds__(512) void k3_feat(
    const unsigned short* __restrict__ W2k,
    const unsigned short* __restrict__ Wck,
    const unsigned short* __restrict__ fmTbf,
    const unsigned char* __restrict__ nfm,
    float* __restrict__ out, int V) {
  __shared__ float red[2][3][16][64];   // 24576 B
  int pb = blockIdx.x, j = blockIdx.y;
  int t = threadIdx.x, w = t >> 6, lane = t & 63;
  int rhalf = w >> 2, kw = w & 3;
  int r = c_C2V[j][rhalf];
  int quad = lane >> 4, col = lane & 15;
  int p0 = pb * 16;
  f32x4 acc[4];
  #pragma unroll
  for (int m = 0; m < 4; ++m) acc[m] = (f32x4){0.f, 0.f, 0.f, 0.f};

  int base24[6];
  #pragma unroll
  for (int ks = 0; ks < 6; ++ks) {
    int ci = ks * 32 + quad * 8;
    int hh = ci / 24, oo = ci - hh * 24;
    base24[ks] = hh * 6912 + oo;   // hh*144*48 + oo (bytes)
  }

  int pA = p0 + col;
  const unsigned char* Bn0 = nfm + (size_t)(pA >> 1) * 55296 + (pA & 1) * 24;
  const unsigned short* Bc0 = fmTbf + (size_t)pA * 192;

  int nkb = (kw == 3) ? 4 : 3;
  for (int i = 0; i < nkb; ++i) {
    int kb = kw * 3 + i;   // kw=3,i=3 -> 12 (center)
    const unsigned short* Ab;
    int kr48 = 0;
    if (kb < 12) { Ab = W2k + (size_t)(kb * 12 + r) * 12288; kr48 = (kb * 12 + r) * 48; }
    else         { Ab = Wck + (size_t)r * 12288; }
    const unsigned short* Albase = Ab + quad * 512 + col * 8;
    #pragma unroll
    for (int ks = 0; ks < 6; ++ks) {
      bf16x8 b0;
      if (kb < 12) {
        b0 = dec8(*(const uint2*)(Bn0 + base24[ks] + kr48));
      } else {
        b0 = *(const bf16x8*)(Bc0 + ks * 32 + quad * 8);
      }
      #pragma unroll
      for (int m = 0; m < 4; ++m) {
        bf16x8 a = *(const bf16x8*)(Albase + ks * 2048 + m * 128);
        acc[m] = __builtin_amdgcn_mfma_f32_16x16x32_bf16(a, b0, acc[m], 0, 0, 0);
      }
    }
  }
  if (kw > 0) {
    #pragma unroll
    for (int m = 0; m < 4; ++m)
      #pragma unroll
      for (int rr = 0; rr < 4; ++rr)
        red[rhalf][kw - 1][m * 4 + rr][lane] = acc[m][rr];
  }
  __syncthreads();
  if (kw == 0) {
    #pragma unroll
    for (int m = 0; m < 4; ++m)
      #pragma unroll
      for (int rr = 0; rr < 4; ++rr) {
        int ri = m * 4 + rr;
        acc[m][rr] += red[rhalf][0][ri][lane] + red[rhalf][1][ri][lane] + red[rhalf][2][ri][lane];
      }
  }
  if (w == 4) {
    #pragma unroll
    for (int m = 0; m < 4; ++m)
      #pragma unroll
      for (int rr = 0; rr < 4; ++rr)
        red[1][0][m * 4 + rr][lane] = acc[m][rr];
  }
  __syncthreads();
  if (w == 0) {
    #pragma unroll
    for (int m = 0; m < 4; ++m)
      #pragma unroll
      for (int rr = 0; rr < 4; ++rr) {
        float vmax = fmaxf(acc[m][rr], red[1][0][m * 4 + rr][lane]);
        int d = m * 16 + quad * 4 + rr;
        out[((size_t)d * V + p0 + col) * 6 + j] = vmax;
      }
  }
}

// ---------- host ----------
extern "C" void kernel_launch(void* const* d_in, const int* in_sizes, int n_in,
                              void* d_out, int out_size, void* d_ws, size_t ws_size,
                              hipStream_t stream) {
  const int* nbi = (const int*)d_in[0];
  const float* verts = (const float*)d_in[1];
  const float* fm = (const float*)d_in[2];
  const float* Wdim = (const float*)d_in[3];
  const float* W = (const float*)d_in[4];
  const float* Wdir = (const float*)d_in[5];
  float* out = (float*)d_out;
  float* ws = (float*)d_ws;
  int V = in_sizes[0] / NN;   // 2048

  unsigned short* A_bf  = (unsigned short*)ws;             // 221184 ush
  unsigned short* W2k   = (unsigned short*)(ws + 110592);  // 1769472 ush
  unsigned short* Wck   = (unsigned short*)(ws + 995328);  // 147456 ush
  unsigned short* fmTbf = (unsigned short*)(ws + 1069056); // 192*V ush
  size_t o = 1069056 + (size_t)96 * V;
  unsigned char* nfm = (unsigned char*)(ws + o);           // 27648*V BYTES [pg][1152][48] int8 biased
  o += (size_t)6912 * V;
  unsigned short* wdB = (unsigned short*)(ws + o);         // 1024 ush

  // k0a: A_bf + wdB only (k12 prerequisites), 27776 threads
  k0a_expand<<<109, 256, 0, stream>>>(Wdir, Wdim, A_bf, wdB);
  // merged: k12 blocks [0, V/2) + k0b blocks [V/2, V/2 + nb0b)
  int n0b = 239616 + 24 * V + 48 * V;            // k0b thread count
  int nb0b = (n0b + 255) / 256;                  // 1512 blocks at V=2048
  k12f_main<<<V / 2 + nb0b, 256, 0, stream>>>(nbi, verts, fm, Wdim, wdB, A_bf, nfm,
                                              W, W2k, Wck, fmTbf,
                                              out + (size_t)DO * V * 6, V);
  k3_feat<<<dim3(V / 16, 6), 512, 0, stream>>>(W2k, Wck, fmTbf, nfm, out, V);
}